// Round 1
// baseline (181.808 us; speedup 1.0000x reference)
//
#include <hip/hip_runtime.h>
#include <math.h>

// DCCA loss, shapes fixed by the reference:
//   H1,H2: (m=2048, n=64, k=128) fp32 after reshape
//   Sigma11/22/12 are 64x64; corr = ||L1^-1 S12 L2^-T||_F via Cholesky
#define MBATCH 2048
#define NDIM 64
#define KDIM 128
#define TILES_PER_BLOCK 4
#define GRID1 (MBATCH / TILES_PER_BLOCK)  // 512 blocks
#define RS 132  // LDS row stride in floats: 128 + 4 pad (16B-aligned rows, 2-way max conflict)

// c = (1 - 1/m)^2 / (m*(m-1)) = 2047 / 2048^3
#define CSCALE 2.3830240e-7f
#define RIDGE 1e-4f

__global__ __launch_bounds__(256) void gram_kernel(const float* __restrict__ H1,
                                                   const float* __restrict__ H2,
                                                   float* __restrict__ sig) {
    __shared__ float X1s[NDIM * RS];
    __shared__ float X2s[NDIM * RS];
    const int tid = threadIdx.x;
    const int tx = tid & 15;   // col group: s = tx + 16*jj
    const int ty = tid >> 4;   // row group: r = ty + 16*j

    float acc11[4][4] = {{0.f}};
    float acc22[4][4] = {{0.f}};
    float acc12[4][4] = {{0.f}};

    const int i0 = blockIdx.x * TILES_PER_BLOCK;
    for (int t = 0; t < TILES_PER_BLOCK; ++t) {
        const size_t base = (size_t)(i0 + t) * (NDIM * KDIM);
        __syncthreads();  // protect LDS from previous iteration's readers
        #pragma unroll
        for (int it = 0; it < 8; ++it) {
            int idx = it * 256 + tid;
            int r = idx >> 5;    // 0..63
            int kq = idx & 31;   // 0..31 (float4 along k)
            float4 v1 = *(const float4*)(H1 + base + r * KDIM + kq * 4);
            float4 v2 = *(const float4*)(H2 + base + r * KDIM + kq * 4);
            *(float4*)&X1s[r * RS + kq * 4] = v1;
            *(float4*)&X2s[r * RS + kq * 4] = v2;
        }
        __syncthreads();

        #pragma unroll 2
        for (int kq = 0; kq < 32; ++kq) {
            float4 a1[4], b1[4], a2[4], b2[4];
            #pragma unroll
            for (int j = 0; j < 4; ++j) {
                a1[j] = *(const float4*)&X1s[(ty + 16 * j) * RS + kq * 4];
                a2[j] = *(const float4*)&X2s[(ty + 16 * j) * RS + kq * 4];
                b1[j] = *(const float4*)&X1s[(tx + 16 * j) * RS + kq * 4];
                b2[j] = *(const float4*)&X2s[(tx + 16 * j) * RS + kq * 4];
            }
            #pragma unroll
            for (int j = 0; j < 4; ++j) {
                #pragma unroll
                for (int jj = 0; jj < 4; ++jj) {
                    acc11[j][jj] += a1[j].x * b1[jj].x + a1[j].y * b1[jj].y +
                                    a1[j].z * b1[jj].z + a1[j].w * b1[jj].w;
                    acc22[j][jj] += a2[j].x * b2[jj].x + a2[j].y * b2[jj].y +
                                    a2[j].z * b2[jj].z + a2[j].w * b2[jj].w;
                    acc12[j][jj] += a1[j].x * b2[jj].x + a1[j].y * b2[jj].y +
                                    a1[j].z * b2[jj].z + a1[j].w * b2[jj].w;
                }
            }
        }
    }

    // Flush: each (r,s) owned by exactly one thread per block -> one atomic per entry per block
    #pragma unroll
    for (int j = 0; j < 4; ++j) {
        #pragma unroll
        for (int jj = 0; jj < 4; ++jj) {
            int r = ty + 16 * j;
            int s = tx + 16 * jj;
            atomicAdd(&sig[r * 64 + s], acc11[j][jj]);
            atomicAdd(&sig[4096 + r * 64 + s], acc22[j][jj]);
            atomicAdd(&sig[8192 + r * 64 + s], acc12[j][jj]);
        }
    }
}

// One block. Scale+ridge, two Choleskys (one wave each, lane = row, L-row kept in
// registers, no barriers needed within a wave), then two fully-unrolled triangular
// solves (y[64]/z[64] in registers, all indices static), Frobenius norm, -sqrt.
__global__ __launch_bounds__(256) void solve_kernel(const float* __restrict__ sig,
                                                    float* __restrict__ out) {
    __shared__ float A1[64 * 68];
    __shared__ float A2[64 * 68];
    __shared__ float S [64 * 68];
    __shared__ float AS[64 * 68];
    __shared__ float Ldi[2][64];
    const int tid = threadIdx.x;

    for (int idx = tid; idx < 4096; idx += 256) {
        int r = idx >> 6, q = idx & 63;
        float rg = (r == q) ? RIDGE : 0.0f;
        A1[r * 68 + q] = CSCALE * sig[idx] + rg;
        A2[r * 68 + q] = CSCALE * sig[4096 + idx] + rg;
        S [r * 68 + q] = CSCALE * sig[8192 + idx];
    }
    __syncthreads();

    if (tid < 128) {
        float* A = (tid >= 64) ? A2 : A1;
        const int half = tid >> 6;
        const int lane = tid & 63;
        float Lrow[64];
        #pragma unroll
        for (int j = 0; j < 64; ++j) {
            float s = A[lane * 68 + j];          // original A[i][j] (col j untouched so far)
            #pragma unroll
            for (int tt = 0; tt < j; ++tt)
                s -= Lrow[tt] * A[j * 68 + tt];  // broadcast read of L row j
            float dj = __shfl(s, j, 64);         // updated diagonal from lane j
            float Ljj = sqrtf(dj);
            float v = s / Ljj;                   // at lane j this equals Ljj
            Lrow[j] = v;
            if (lane >= j) A[lane * 68 + j] = v; // store L column j
            if (lane == j) Ldi[half][j] = 1.0f / Ljj;
        }
    }
    __syncthreads();

    // Solve L1 * Y = S12  (thread c owns column c)
    if (tid < 64) {
        const int c = tid;
        float y[64];
        #pragma unroll
        for (int r = 0; r < 64; ++r) {
            float s = S[r * 68 + c];
            #pragma unroll
            for (int tt = 0; tt < r; ++tt) s -= A1[r * 68 + tt] * y[tt];
            y[r] = s * Ldi[0][r];
            AS[r * 68 + c] = y[r];
        }
    }
    __syncthreads();

    // Solve L2 * Z = Y^T row-wise (thread c owns row c of Y); accumulate ||Z||^2
    if (tid < 64) {
        const int c = tid;
        float z[64];
        float nrm = 0.0f;
        #pragma unroll
        for (int r = 0; r < 64; ++r) {
            float s = AS[c * 68 + r];
            #pragma unroll
            for (int tt = 0; tt < r; ++tt) s -= A2[r * 68 + tt] * z[tt];
            z[r] = s * Ldi[1][r];
            nrm += z[r] * z[r];
        }
        #pragma unroll
        for (int off = 32; off; off >>= 1) nrm += __shfl_xor(nrm, off, 64);
        if (tid == 0) out[0] = -sqrtf(nrm);
    }
}

extern "C" void kernel_launch(void* const* d_in, const int* in_sizes, int n_in,
                              void* d_out, int out_size, void* d_ws, size_t ws_size,
                              hipStream_t stream) {
    const float* H1 = (const float*)d_in[0];
    const float* H2 = (const float*)d_in[1];
    float* sig = (float*)d_ws;  // 3 * 4096 floats = 48 KB accumulators

    hipMemsetAsync(d_ws, 0, 3 * 4096 * sizeof(float), stream);
    gram_kernel<<<GRID1, 256, 0, stream>>>(H1, H2, sig);
    solve_kernel<<<1, 256, 0, stream>>>(sig, (float*)d_out);
}